// Round 1
// baseline (4864.878 us; speedup 1.0000x reference)
//
#include <hip/hip_runtime.h>
#include <hip/hip_bf16.h>
#include <stdint.h>

#define TT 4096
#define EE 256
#define LL 20
#define STARTT 18
#define STOPP 19
#define NEGV -10000.0f
#define NCH 256   // TT/16

typedef short v8s __attribute__((ext_vector_type(8)));
typedef float v4f __attribute__((ext_vector_type(4)));

// ---------- helpers ----------
__device__ inline float bf2f(unsigned short u){
  unsigned int x = ((unsigned int)u) << 16;
  return __builtin_bit_cast(float, x);
}
__device__ inline unsigned short f2bf(float f){
  unsigned int x = __builtin_bit_cast(unsigned int, f);
  unsigned int r = (x + 0x7FFFu + ((x >> 16) & 1u)) >> 16;
  return (unsigned short)r;
}

#if __has_builtin(__builtin_amdgcn_sdot4)
#define SDOT4(a,b,c) __builtin_amdgcn_sdot4((int)(a),(int)(b),(c),false)
#else
__device__ inline int sdot4_sw(int a, int b, int c){
  return c + (int)(char)(a)        * (int)(char)(b)
           + (int)(char)(a >> 8)   * (int)(char)(b >> 8)
           + (int)(char)(a >> 16)  * (int)(char)(b >> 16)
           + (int)(char)(a >> 24)  * (int)(char)(b >> 24);
}
#define SDOT4(a,b,c) sdot4_sw((int)(a),(int)(b),(c))
#endif

// lgkm-only barrier: syncs LDS without draining outstanding global (vmcnt) prefetch
#define BARRIER_LDS() asm volatile("s_waitcnt lgkmcnt(0)\ns_barrier" ::: "memory")

// ---------- workspace layout (bytes) ----------
constexpr size_t OFF_U    = 0;                              // bf16 [2][T][1024] (PERMUTED cols = lstm thread id)
constexpr size_t SZ_U     = 2ull*TT*1024*2;
constexpr size_t OFF_X    = OFF_U + SZ_U;                   // bf16 [T][E]
constexpr size_t SZ_X     = (size_t)TT*EE*2;
constexpr size_t OFF_WIH  = OFF_X + SZ_X;                   // bf16 [2048][256]
constexpr size_t SZ_WIH   = 2048ull*256*2;
constexpr size_t OFF_BIAS = OFF_WIH + SZ_WIH;               // f32 [2048]
constexpr size_t SZ_BIAS  = 2048ull*4;
constexpr size_t OFF_WQ   = OFF_BIAS + SZ_BIAS;             // uint4 [2][16][1024] (i8 packed, PERMUTED cols)
constexpr size_t SZ_WQ    = 2ull*16*1024*16;
constexpr size_t OFF_FS   = OFF_WQ + SZ_WQ;                 // f32 [2][1024] (PERMUTED)
constexpr size_t SZ_FS    = 2ull*1024*4;
constexpr size_t OFF_WOP  = OFF_FS + SZ_FS;                 // bf16 [32][512]
constexpr size_t SZ_WOP   = 32ull*512*2;
constexpr size_t OFF_HOUT = OFF_WOP + SZ_WOP;               // bf16 [T][512]
constexpr size_t SZ_HOUT  = (size_t)TT*512*2;
constexpr size_t OFF_FE   = OFF_HOUT + SZ_HOUT;             // f32 [T][20]
constexpr size_t SZ_FE    = (size_t)TT*LL*4;
constexpr size_t OFF_P    = OFF_FE + SZ_FE;                 // f32 [256][20][20]
constexpr size_t SZ_P     = 256ull*400*4;
constexpr size_t OFF_BAL  = OFF_P + SZ_P;                   // f32 [257][20]
constexpr size_t SZ_BAL   = 20736;
constexpr size_t OFF_BP   = OFF_BAL + SZ_BAL;               // u8 [T][20]
constexpr size_t SZ_BP    = (size_t)TT*LL;
constexpr size_t OFF_M    = OFF_BP + SZ_BP;                 // u8 [256][20]
constexpr size_t SZ_M     = 256ull*LL;
constexpr size_t OFF_EG   = OFF_M + SZ_M + 64;              // i32 [256]

// Row permutation: lstm thread t owns gate-row row(t) = g*256 + w*16 + i,
// where w = t>>6 (wave), g = (t>>4)&3 (gate subgroup), i = t&15.
// Inverse (storage column for true row R): col = ((R>>4)&15)*64 + (R>>8)*16 + (R&15).
__device__ inline int row2col(int R){
  return ((R >> 4) & 15) * 64 + (R >> 8) * 16 + (R & 15);
}

// ---------- prep kernels ----------

__global__ void k_gather(const int* __restrict__ x, const float* __restrict__ emb,
                         unsigned short* __restrict__ X){
  int t = blockIdx.x;
  int xt = x[t];
  const float4* src = (const float4*)(emb + (size_t)xt * EE);
  float4 v = src[threadIdx.x];
  ushort4 o;
  o.x = f2bf(v.x); o.y = f2bf(v.y); o.z = f2bf(v.z); o.w = f2bf(v.w);
  ((ushort4*)(X + (size_t)t * EE))[threadIdx.x] = o;
}

__global__ void k_wih(const float* __restrict__ wf, const float* __restrict__ wb,
                      unsigned short* __restrict__ WIH){
  int gid = blockIdx.x * 256 + threadIdx.x;   // 65536
  int row = gid >> 5, c8 = gid & 31;
  const float* src = (row < 1024 ? wf + (size_t)row * EE : wb + (size_t)(row - 1024) * EE) + c8 * 8;
  unsigned short* dst = WIH + (size_t)row * 256 + c8 * 8;
#pragma unroll
  for (int i = 0; i < 8; i++) dst[i] = f2bf(src[i]);
}

__global__ void k_bias(const float* bf, const float* hf, const float* bb, const float* hb,
                       float* __restrict__ bias){
  int i = blockIdx.x * 256 + threadIdx.x;     // 2048
  int r = i & 1023;
  bias[i] = (i < 1024) ? (bf[r] + hf[r]) : (bb[r] + hb[r]);
}

// w_out -> bf16, padded to 32 rows
__global__ void k_wout(const float* __restrict__ wout, unsigned short* __restrict__ WOP){
  int gid = blockIdx.x * 256 + threadIdx.x;   // 16384 = 32*512
  int row = gid >> 9, k = gid & 511;
  WOP[gid] = (row < LL) ? f2bf(wout[row * 512 + k]) : 0;
}

// quantize W_hh rows to int8 with per-row scale, stored at PERMUTED column.
// WQ uint4 layout: [(d*16 + q4)*1024 + col] = cols 16*q4..16*q4+15 of row R, col = row2col(R).
// FS: [d*1024 + col] = rowmax/127
__global__ void k_whh5(const float* __restrict__ whf, const float* __restrict__ whb,
                       unsigned int* __restrict__ WQ, float* __restrict__ FS){
  int row = blockIdx.x;       // 0..2047
  int d = row >> 10, R = row & 1023;
  const float* W = (d ? whb : whf) + (size_t)R * 256;
  int t = threadIdx.x;        // 0..63 ; covers cols 4t..4t+3
  float4 v = ((const float4*)W)[t];
  float m = fmaxf(fmaxf(fabsf(v.x), fabsf(v.y)), fmaxf(fabsf(v.z), fabsf(v.w)));
#pragma unroll
  for (int o = 32; o >= 1; o >>= 1) m = fmaxf(m, __shfl_down(m, o));
  m = __shfl(m, 0);
  float sc = (m > 0.f) ? (m / 127.f) : 1.f;
  float inv = 1.f / sc;
  int a = (int)rintf(v.x * inv), b = (int)rintf(v.y * inv);
  int c = (int)rintf(v.z * inv), e = (int)rintf(v.w * inv);
  unsigned int pack = ((unsigned)a & 255u) | (((unsigned)b & 255u) << 8)
                    | (((unsigned)c & 255u) << 16) | (((unsigned)e & 255u) << 24);
  int q4 = t >> 2, comp = t & 3;
  int col = row2col(R);
  WQ[(((size_t)(d * 16 + q4)) * 1024 + col) * 4 + comp] = pack;
  if (t == 0) FS[d * 1024 + col] = sc;
}

// U[d][t][col] = bf16( X[t]·W_ih row r + bias ), col = row2col(r), via 16x16x32 bf16 MFMA
__global__ void k_gemm_u(const unsigned short* __restrict__ X,
                         const unsigned short* __restrict__ WIH,
                         const float* __restrict__ bias,
                         unsigned short* __restrict__ U){
  int wave = threadIdx.x >> 6, l = threadIdx.x & 63;
  int tile = blockIdx.x * 4 + wave;           // 0..32767
  int mt = tile & 255, nt = tile >> 8;        // 256 x 128 tiles
  int lm = l & 15, lq = l >> 4;
  const unsigned short* Arow = X   + (size_t)(mt * 16 + lm) * 256 + lq * 8;
  const unsigned short* Brow = WIH + (size_t)(nt * 16 + lm) * 256 + lq * 8;
  v4f acc = {0.f, 0.f, 0.f, 0.f};
#pragma unroll
  for (int kb = 0; kb < 8; kb++){
    v8s a = *(const v8s*)(Arow + kb * 32);
    v8s b = *(const v8s*)(Brow + kb * 32);
    acc = __builtin_amdgcn_mfma_f32_16x16x32_bf16(a, b, acc, 0, 0, 0);
  }
  int n = nt * 16 + lm;                       // 0..2047 gate-row
  int dd = n >> 10, r = n & 1023;
  int cp = row2col(r);
  float bi = bias[n];
#pragma unroll
  for (int r4 = 0; r4 < 4; r4++){
    int t = mt * 16 + lq * 4 + r4;
    U[((size_t)(dd * TT + t)) * 1024 + cp] = f2bf(acc[r4] + bi);
  }
}

// ---------- the recurrent core ----------
// grid=2 (one CU per direction), block=1024 (16 waves, 4/SIMD pinned).
// Wave w owns hidden elements j = 16w..16w+15; lane l computes gate g=(l>>4)
// of element j = 16w + (l&15): all 4 gates of an element live in ONE wave, so
// the z exchange is 4 in-wave ds_bpermute shuffles — no zbuf, ONE barrier per
// step (hb double-buffered; write-side and next read-side separated by it).
// Activations applied per-lane pre-exchange by all 16 waves via the unified
// form act = fma(-C1, e, 1)*rcp(1+e), e = exp(E0*clamp(z,±CB)):
//   sigmoid: E0=-1, C1=0, CB=87 ; tanh: E0=-2, C1=1, CB=20.
// Weights: 64 u32 packed-i8 VGPRs per thread, pinned resident.

#define Q16(M) M(0) M(1) M(2) M(3) M(4) M(5) M(6) M(7) \
               M(8) M(9) M(10) M(11) M(12) M(13) M(14) M(15)

#define DECLW(q) unsigned wx_##q, wy_##q, wz_##q, ww_##q;
#define LOADW(q) { uint4 _tw = WQ4[wbase + (q) * 1024]; \
                   wx_##q = _tw.x; wy_##q = _tw.y; wz_##q = _tw.z; ww_##q = _tw.w; }
#define PINW(q) asm volatile("" : "+v"(wx_##q), "+v"(wy_##q), "+v"(wz_##q), "+v"(ww_##q));
// 4 independent accumulator chains (integer-exact regardless of order)
#define DOT4X(q, A) { uint4 _h = hq[q]; \
                  A = SDOT4(wx_##q, _h.x, A); A = SDOT4(wy_##q, _h.y, A); \
                  A = SDOT4(wz_##q, _h.z, A); A = SDOT4(ww_##q, _h.w, A); }

__global__ void __launch_bounds__(1024)
__attribute__((amdgpu_waves_per_eu(4, 4)))
k_lstm8(
    const unsigned short* __restrict__ U, const uint4* __restrict__ WQ4,
    const float* __restrict__ FS, const float* __restrict__ h0,
    const float* __restrict__ c0, unsigned short* __restrict__ hout){
  int d = blockIdx.x;
  int t = threadIdx.x;
  int l = t & 63;
  int g = l >> 4;               // gate subgroup: 0=i 1=f 2=g 3=o
  int i16 = l & 15;
  int w = t >> 6;
  int j = w * 16 + i16;         // hidden element owned (replicated over g)

  __shared__ __align__(16) unsigned char hb[2][256];

  Q16(DECLW)
  {
    size_t wbase = (size_t)d * 16 * 1024 + t;
    Q16(LOADW)
  }
  Q16(PINW)

  float fs  = FS[d * 1024 + t];
  float fs8 = fs * (8.f / 127.f);   // step 0: h0 quant range ±8
  float fs1 = fs * (1.f / 127.f);   // steps >=1: h in (-1,1)

  // per-lane activation constants
  float CB = (g == 2) ? 20.f : 87.f;
  float E0 = (g == 2) ? -2.f : -1.f;
  float C1 = (g == 2) ? 1.f  : 0.f;

  float cst = c0[d * 256 + j];      // replicated 4x across gate subgroups
  if (l < 16){
    float hini = h0[d * 256 + j];
    hini = fminf(fmaxf(hini, -8.f), 8.f);
    hb[0][j] = (unsigned char)(char)(int)rintf(hini * (127.f / 8.f));
  }

  const unsigned short* Up = U + (size_t)d * TT * 1024 + t;
  int stp = d ? -1 : 1;
  int tA = d ? TT - 1 : 0;
  unsigned short u_c = Up[(size_t)tA * 1024];
  unsigned short u_n = Up[(size_t)(tA + stp) * 1024];

  unsigned short* hp = hout + (size_t)tA * 512 + d * 256 + j;

  __syncthreads();

  for (int s = 0; s < TT; s++){
    int par = s & 1;
    int tt = d ? (TT - 1 - s) : s;
    const uint4* hq = (const uint4*)(&hb[par][0]);   // uniform → broadcast reads

    int a0 = 0, a1 = 0, a2 = 0, a3 = 0;
    DOT4X(0, a0)  DOT4X(1, a1)  DOT4X(2, a2)  DOT4X(3, a3)
    DOT4X(4, a0)  DOT4X(5, a1)  DOT4X(6, a2)  DOT4X(7, a3)
    DOT4X(8, a0)  DOT4X(9, a1)  DOT4X(10, a2) DOT4X(11, a3)
    DOT4X(12, a0) DOT4X(13, a1) DOT4X(14, a2) DOT4X(15, a3)
    int a = (a0 + a1) + (a2 + a3);

    float fsh = (s == 0) ? fs8 : fs1;
    float z = bf2f(u_c) + (float)a * fsh;

    // rotate u prefetch (2 steps ahead; clamped always-load, uniform addr math)
    u_c = u_n;
    {
      int t2 = tt + 2 * stp;
      t2 = t2 < 0 ? 0 : (t2 > TT - 1 ? TT - 1 : t2);
      u_n = Up[(size_t)t2 * 1024];
    }

    // own-gate activation (all 16 waves in parallel)
    float zc = fminf(fmaxf(z, -CB), CB);
    float e = __expf(E0 * zc);
    float act = fmaf(-C1, e, 1.f) * __builtin_amdgcn_rcpf(1.f + e);

    // in-wave gather of the 4 gate activations for element j
    float gi = __shfl(act, i16,      64);
    float gf = __shfl(act, i16 + 16, 64);
    float gg = __shfl(act, i16 + 32, 64);
    float go = __shfl(act, i16 + 48, 64);

    cst = fmaf(gf, cst, gi * gg);
    float cc = fminf(fmaxf(cst, -20.f), 20.f);
    float e2 = __expf(-2.f * cc);
    float th = (1.f - e2) * __builtin_amdgcn_rcpf(1.f + e2);
    float h = go * th;

    if (g == 0){
      int qv = (int)rintf(fminf(fmaxf(h, -1.f), 1.f) * 127.f);
      hb[par ^ 1][j] = (unsigned char)(char)qv;     // 16 bytes per wave
    } else if (g == 1){
      *hp = f2bf(h);                                // 32 B contiguous per wave
    }
    hp += stp * 512;

    BARRIER_LDS();
  }
}

// feats via MFMA: FE[t][j] = HOUT[t]·WOP[j] + bout[j], WOP padded to 32 rows
__global__ void k_feats2(const unsigned short* __restrict__ HOUT,
                         const unsigned short* __restrict__ WOP,
                         const float* __restrict__ bout,
                         float* __restrict__ feats){
  int wave = threadIdx.x >> 6, l = threadIdx.x & 63;
  int tile = blockIdx.x * 4 + wave;           // 0..511
  int mt = tile & 255, nt = tile >> 8;        // 256 M-tiles x 2 N-tiles
  int lm = l & 15, lq = l >> 4;
  const unsigned short* Arow = HOUT + (size_t)(mt * 16 + lm) * 512 + lq * 8;
  const unsigned short* Brow = WOP  + (size_t)(nt * 16 + lm) * 512 + lq * 8;
  v4f acc = {0.f, 0.f, 0.f, 0.f};
#pragma unroll
  for (int kb = 0; kb < 16; kb++){
    v8s a = *(const v8s*)(Arow + kb * 32);
    v8s b = *(const v8s*)(Brow + kb * 32);
    acc = __builtin_amdgcn_mfma_f32_16x16x32_bf16(a, b, acc, 0, 0, 0);
  }
  int n = nt * 16 + lm;
  if (n < LL){
    float bi = bout[n];
#pragma unroll
    for (int r4 = 0; r4 < 4; r4++){
      int t = mt * 16 + lq * 4 + r4;
      feats[t * LL + n] = acc[r4] + bi;
    }
  }
}

// V1: per-chunk max-plus matrix product
__global__ void k_vchunk(const float* __restrict__ feats, const float* __restrict__ trans,
                         float* __restrict__ P){
  int c = blockIdx.x, j = threadIdx.x;
  __shared__ float Ps[2][LL][LL];
  bool act = j < LL;
  float trow[LL];
  if (act){
#pragma unroll
    for (int i = 0; i < LL; i++) trow[i] = trans[j * LL + i];
    for (int i = 0; i < LL; i++) Ps[0][i][j] = (i == j) ? 0.f : -1e30f;
  }
  __syncthreads();
  for (int s = 0; s < 16; s++){
    int t = c * 16 + s;
    int pb = s & 1;
    if (act){
      float fj = feats[t * LL + j];
      for (int i = 0; i < LL; i++){
        float m = Ps[pb][i][0] + trow[0];
#pragma unroll
        for (int mm = 1; mm < LL; mm++) m = fmaxf(m, Ps[pb][i][mm] + trow[mm]);
        Ps[pb ^ 1][i][j] = m + fj;
      }
    }
    __syncthreads();
  }
  if (act)
    for (int i = 0; i < LL; i++) P[((size_t)c * LL + i) * LL + j] = Ps[0][i][j];
}

// V2: sequential boundary-alpha scan (prefetch-pipelined)
__global__ void k_vscan(const float* __restrict__ P, float* __restrict__ bal){
  int tid = threadIdx.x;
  bool act = tid < LL;
  __shared__ float al[LL];
  __shared__ float Pl[400];
  if (act){
    float a = (tid == STARTT) ? 0.f : NEGV;
    al[tid] = a;
    bal[tid] = a;
  }
  for (int k = tid; k < 400; k += 64) Pl[k] = P[k];
  __syncthreads();
  for (int c = 0; c < NCH; c++){
    float p0 = 0.f, p1 = 0.f, p2 = 0.f, p3 = 0.f, p4 = 0.f, p5 = 0.f, p6 = 0.f;
    if (c + 1 < NCH){
      const float* Pn = P + (size_t)(c + 1) * 400;
      p0 = Pn[tid];        p1 = Pn[tid + 64];  p2 = Pn[tid + 128];
      p3 = Pn[tid + 192];  p4 = Pn[tid + 256]; p5 = Pn[tid + 320];
      if (tid + 384 < 400) p6 = Pn[tid + 384];
    }
    float m = -1e30f;
    if (act){
      m = al[0] + Pl[tid];
#pragma unroll
      for (int i = 1; i < LL; i++) m = fmaxf(m, al[i] + Pl[i * LL + tid]);
    }
    __syncthreads();
    if (act){
      al[tid] = m;
      bal[(c + 1) * LL + tid] = m;
    }
    if (c + 1 < NCH){
      Pl[tid] = p0;        Pl[tid + 64] = p1;  Pl[tid + 128] = p2;
      Pl[tid + 192] = p3;  Pl[tid + 256] = p4; Pl[tid + 320] = p5;
      if (tid + 384 < 400) Pl[tid + 384] = p6;
    }
    __syncthreads();
  }
}

// V3: per-chunk backpointers + chunk backtrace map
__global__ void k_vbp(const float* __restrict__ feats, const float* __restrict__ trans,
                      const float* __restrict__ bal, unsigned char* __restrict__ bp,
                      unsigned char* __restrict__ M){
  int c = blockIdx.x, j = threadIdx.x;
  bool act = j < LL;
  __shared__ float al[2][LL];
  __shared__ unsigned char bpl[16][LL];
  float trow[LL];
  if (act){
#pragma unroll
    for (int i = 0; i < LL; i++) trow[i] = trans[j * LL + i];
    al[0][j] = bal[c * LL + j];
  }
  __syncthreads();
  for (int s = 0; s < 16; s++){
    int t = c * 16 + s;
    int pb = s & 1;
    if (act){
      float m = al[pb][0] + trow[0];
      int arg = 0;
#pragma unroll
      for (int i = 1; i < LL; i++){
        float v = al[pb][i] + trow[i];
        if (v > m){ m = v; arg = i; }
      }
      bpl[s][j] = (unsigned char)arg;
      bp[(size_t)t * LL + j] = (unsigned char)arg;
      al[pb ^ 1][j] = m + feats[t * LL + j];
    }
    __syncthreads();
  }
  if (act){
    int tag = j;
    for (int s = 15; s >= 0; s--) tag = bpl[s][tag];
    M[c * LL + j] = (unsigned char)tag;
  }
}

// V4: final score + chunk-boundary tag chase
__global__ void k_vtag(const float* __restrict__ bal, const float* __restrict__ trans,
                       const unsigned char* __restrict__ M, int* __restrict__ Eg,
                       float* __restrict__ out){
  int tid = threadIdx.x;
  __shared__ unsigned char Ml[NCH * LL];
  __shared__ float fin[LL];
  for (int k = tid; k < NCH * LL; k += 64) Ml[k] = M[k];
  if (tid < LL) fin[tid] = bal[NCH * LL + tid] + trans[STOPP * LL + tid];
  __syncthreads();
  if (tid == 0){
    float m = fin[0]; int arg = 0;
    for (int i = 1; i < LL; i++) if (fin[i] > m){ m = fin[i]; arg = i; }
    out[0] = m;
    int tag = arg;
    Eg[NCH - 1] = tag;
    for (int c = NCH - 1; c >= 1; c--){
      tag = Ml[c * LL + tag];
      Eg[c - 1] = tag;
    }
  }
}

// V5: parallel path emission
__global__ void k_vemit(const int* __restrict__ Eg, const unsigned char* __restrict__ bp,
                        float* __restrict__ out){
  int c = threadIdx.x;
  int tag = Eg[c];
  out[1 + c * 16 + 15] = (float)tag;
  for (int s = 15; s >= 1; s--){
    tag = bp[(size_t)(c * 16 + s) * LL + tag];
    out[1 + c * 16 + s - 1] = (float)tag;
  }
}

// ---------- launcher ----------
extern "C" void kernel_launch(void* const* d_in, const int* in_sizes, int n_in,
                              void* d_out, int out_size, void* d_ws, size_t ws_size,
                              hipStream_t stream){
  (void)in_sizes; (void)n_in; (void)out_size; (void)ws_size;
  const int*   x     = (const int*)d_in[0];
  const float* emb   = (const float*)d_in[1];
  const float* wihf  = (const float*)d_in[2];
  const float* whhf  = (const float*)d_in[3];
  const float* bihf  = (const float*)d_in[4];
  const float* bhhf  = (const float*)d_in[5];
  const float* wihb  = (const float*)d_in[6];
  const float* whhb  = (const float*)d_in[7];
  const float* bihb  = (const float*)d_in[8];
  const float* bhhb  = (const float*)d_in[9];
  const float* wout  = (const float*)d_in[10];
  const float* bout  = (const float*)d_in[11];
  const float* trans = (const float*)d_in[12];
  const float* h0    = (const float*)d_in[13];
  const float* c0    = (const float*)d_in[14];
  float* out = (float*)d_out;
  char* ws = (char*)d_ws;

  unsigned short* U    = (unsigned short*)(ws + OFF_U);
  unsigned short* X    = (unsigned short*)(ws + OFF_X);
  unsigned short* WIH  = (unsigned short*)(ws + OFF_WIH);
  float*          BIAS = (float*)(ws + OFF_BIAS);
  unsigned int*   WQ   = (unsigned int*)(ws + OFF_WQ);
  float*          FS   = (float*)(ws + OFF_FS);
  unsigned short* WOP  = (unsigned short*)(ws + OFF_WOP);
  unsigned short* HOUT = (unsigned short*)(ws + OFF_HOUT);
  float*          FE   = (float*)(ws + OFF_FE);
  float*          P    = (float*)(ws + OFF_P);
  float*          BAL  = (float*)(ws + OFF_BAL);
  unsigned char*  BP   = (unsigned char*)(ws + OFF_BP);
  unsigned char*  M    = (unsigned char*)(ws + OFF_M);
  int*            EG   = (int*)(ws + OFF_EG);

  k_gather<<<TT, 64, 0, stream>>>(x, emb, X);
  k_wih<<<256, 256, 0, stream>>>(wihf, wihb, WIH);
  k_bias<<<8, 256, 0, stream>>>(bihf, bhhf, bihb, bhhb, BIAS);
  k_wout<<<64, 256, 0, stream>>>(wout, WOP);
  k_whh5<<<2048, 64, 0, stream>>>(whhf, whhb, WQ, FS);
  k_gemm_u<<<8192, 256, 0, stream>>>(X, WIH, BIAS, U);
  k_lstm8<<<2, 1024, 0, stream>>>(U, (const uint4*)WQ, FS, h0, c0, HOUT);
  k_feats2<<<128, 256, 0, stream>>>(HOUT, WOP, bout, FE);
  k_vchunk<<<NCH, 64, 0, stream>>>(FE, trans, P);
  k_vscan<<<1, 64, 0, stream>>>(P, BAL);
  k_vbp<<<NCH, 64, 0, stream>>>(FE, trans, BAL, BP, M);
  k_vtag<<<1, 64, 0, stream>>>(BAL, trans, M, EG, out);
  k_vemit<<<1, 256, 0, stream>>>(EG, BP, out);
}

// Round 2
// 4425.614 us; speedup vs baseline: 1.0993x; 1.0993x over previous
//
#include <hip/hip_runtime.h>
#include <hip/hip_bf16.h>
#include <stdint.h>

#define TT 4096
#define EE 256
#define LL 20
#define STARTT 18
#define STOPP 19
#define NEGV -10000.0f
#define NCH 256   // TT/16

typedef short v8s __attribute__((ext_vector_type(8)));
typedef float v4f __attribute__((ext_vector_type(4)));

// ---------- helpers ----------
__device__ inline float bf2f(unsigned short u){
  unsigned int x = ((unsigned int)u) << 16;
  return __builtin_bit_cast(float, x);
}
__device__ inline unsigned short f2bf(float f){
  unsigned int x = __builtin_bit_cast(unsigned int, f);
  unsigned int r = (x + 0x7FFFu + ((x >> 16) & 1u)) >> 16;
  return (unsigned short)r;
}

#if __has_builtin(__builtin_amdgcn_sdot4)
#define SDOT4(a,b,c) __builtin_amdgcn_sdot4((int)(a),(int)(b),(c),false)
#else
__device__ inline int sdot4_sw(int a, int b, int c){
  return c + (int)(char)(a)        * (int)(char)(b)
           + (int)(char)(a >> 8)   * (int)(char)(b >> 8)
           + (int)(char)(a >> 16)  * (int)(char)(b >> 16)
           + (int)(char)(a >> 24)  * (int)(char)(b >> 24);
}
#define SDOT4(a,b,c) sdot4_sw((int)(a),(int)(b),(c))
#endif

// lgkm-only barrier: syncs LDS without draining outstanding global (vmcnt) prefetch
#define BARRIER_LDS() asm volatile("s_waitcnt lgkmcnt(0)\ns_barrier" ::: "memory")

// ---------- workspace layout (bytes) ----------
constexpr size_t OFF_U    = 0;                              // bf16 [2][T][1024] (PERMUTED cols)
constexpr size_t SZ_U     = 2ull*TT*1024*2;
constexpr size_t OFF_X    = OFF_U + SZ_U;                   // bf16 [T][E]
constexpr size_t SZ_X     = (size_t)TT*EE*2;
constexpr size_t OFF_WIH  = OFF_X + SZ_X;                   // bf16 [2048][256]
constexpr size_t SZ_WIH   = 2048ull*256*2;
constexpr size_t OFF_BIAS = OFF_WIH + SZ_WIH;               // f32 [2048]
constexpr size_t SZ_BIAS  = 2048ull*4;
constexpr size_t OFF_WQ   = OFF_BIAS + SZ_BIAS;             // uint4 [2][16][1024] (i8 packed, PERMUTED cols)
constexpr size_t SZ_WQ    = 2ull*16*1024*16;
constexpr size_t OFF_FS   = OFF_WQ + SZ_WQ;                 // f32 [2][1024] (PERMUTED)
constexpr size_t SZ_FS    = 2ull*1024*4;
constexpr size_t OFF_WOP  = OFF_FS + SZ_FS;                 // bf16 [32][512]
constexpr size_t SZ_WOP   = 32ull*512*2;
constexpr size_t OFF_HOUT = OFF_WOP + SZ_WOP;               // bf16 [T][512]
constexpr size_t SZ_HOUT  = (size_t)TT*512*2;
constexpr size_t OFF_FE   = OFF_HOUT + SZ_HOUT;             // f32 [T][20]
constexpr size_t SZ_FE    = (size_t)TT*LL*4;
constexpr size_t OFF_P    = OFF_FE + SZ_FE;                 // f32 [256][20][20]
constexpr size_t SZ_P     = 256ull*400*4;
constexpr size_t OFF_BAL  = OFF_P + SZ_P;                   // f32 [257][20]
constexpr size_t SZ_BAL   = 20736;
constexpr size_t OFF_BP   = OFF_BAL + SZ_BAL;               // u8 [T][20]
constexpr size_t SZ_BP    = (size_t)TT*LL;
constexpr size_t OFF_M    = OFF_BP + SZ_BP;                 // u8 [256][20]
constexpr size_t SZ_M     = 256ull*LL;
constexpr size_t OFF_EG   = OFF_M + SZ_M + 64;              // i32 [256]

// Row permutation for the 8-wave / 2-rows-per-lane core:
// lane (w, l) with p = l>>5, e = l&31, J = w*32+e owns
//   rowA = p*256 + J       (gate i or f; sigmoid)  -> colA = w*64 + l
//   rowB = (p+2)*256 + J   (gate g or o)           -> colB = 512 + w*64 + l
// Inverse: row R: g = R>>8, J = R&255:
//   col = (g>>1)*512 + (J>>5)*64 + (g&1)*32 + (J&31)
__device__ inline int row2col(int R){
  int g = R >> 8, J = R & 255;
  return (g >> 1) * 512 + (J >> 5) * 64 + (g & 1) * 32 + (J & 31);
}

// ---------- prep kernels ----------

__global__ void k_gather(const int* __restrict__ x, const float* __restrict__ emb,
                         unsigned short* __restrict__ X){
  int t = blockIdx.x;
  int xt = x[t];
  const float4* src = (const float4*)(emb + (size_t)xt * EE);
  float4 v = src[threadIdx.x];
  ushort4 o;
  o.x = f2bf(v.x); o.y = f2bf(v.y); o.z = f2bf(v.z); o.w = f2bf(v.w);
  ((ushort4*)(X + (size_t)t * EE))[threadIdx.x] = o;
}

__global__ void k_wih(const float* __restrict__ wf, const float* __restrict__ wb,
                      unsigned short* __restrict__ WIH){
  int gid = blockIdx.x * 256 + threadIdx.x;   // 65536
  int row = gid >> 5, c8 = gid & 31;
  const float* src = (row < 1024 ? wf + (size_t)row * EE : wb + (size_t)(row - 1024) * EE) + c8 * 8;
  unsigned short* dst = WIH + (size_t)row * 256 + c8 * 8;
#pragma unroll
  for (int i = 0; i < 8; i++) dst[i] = f2bf(src[i]);
}

__global__ void k_bias(const float* bf, const float* hf, const float* bb, const float* hb,
                       float* __restrict__ bias){
  int i = blockIdx.x * 256 + threadIdx.x;     // 2048
  int r = i & 1023;
  bias[i] = (i < 1024) ? (bf[r] + hf[r]) : (bb[r] + hb[r]);
}

// w_out -> bf16, padded to 32 rows
__global__ void k_wout(const float* __restrict__ wout, unsigned short* __restrict__ WOP){
  int gid = blockIdx.x * 256 + threadIdx.x;   // 16384 = 32*512
  int row = gid >> 9, k = gid & 511;
  WOP[gid] = (row < LL) ? f2bf(wout[row * 512 + k]) : 0;
}

// quantize W_hh rows to int8 with per-row scale, stored at PERMUTED column.
__global__ void k_whh5(const float* __restrict__ whf, const float* __restrict__ whb,
                       unsigned int* __restrict__ WQ, float* __restrict__ FS){
  int row = blockIdx.x;       // 0..2047
  int d = row >> 10, R = row & 1023;
  const float* W = (d ? whb : whf) + (size_t)R * 256;
  int t = threadIdx.x;        // 0..63 ; covers cols 4t..4t+3
  float4 v = ((const float4*)W)[t];
  float m = fmaxf(fmaxf(fabsf(v.x), fabsf(v.y)), fmaxf(fabsf(v.z), fabsf(v.w)));
#pragma unroll
  for (int o = 32; o >= 1; o >>= 1) m = fmaxf(m, __shfl_down(m, o));
  m = __shfl(m, 0);
  float sc = (m > 0.f) ? (m / 127.f) : 1.f;
  float inv = 1.f / sc;
  int a = (int)rintf(v.x * inv), b = (int)rintf(v.y * inv);
  int c = (int)rintf(v.z * inv), e = (int)rintf(v.w * inv);
  unsigned int pack = ((unsigned)a & 255u) | (((unsigned)b & 255u) << 8)
                    | (((unsigned)c & 255u) << 16) | (((unsigned)e & 255u) << 24);
  int q4 = t >> 2, comp = t & 3;
  int col = row2col(R);
  WQ[(((size_t)(d * 16 + q4)) * 1024 + col) * 4 + comp] = pack;
  if (t == 0) FS[d * 1024 + col] = sc;
}

// U[d][t][col] = bf16( X[t]·W_ih row r + bias ), col = row2col(r), via 16x16x32 bf16 MFMA
__global__ void k_gemm_u(const unsigned short* __restrict__ X,
                         const unsigned short* __restrict__ WIH,
                         const float* __restrict__ bias,
                         unsigned short* __restrict__ U){
  int wave = threadIdx.x >> 6, l = threadIdx.x & 63;
  int tile = blockIdx.x * 4 + wave;           // 0..32767
  int mt = tile & 255, nt = tile >> 8;        // 256 x 128 tiles
  int lm = l & 15, lq = l >> 4;
  const unsigned short* Arow = X   + (size_t)(mt * 16 + lm) * 256 + lq * 8;
  const unsigned short* Brow = WIH + (size_t)(nt * 16 + lm) * 256 + lq * 8;
  v4f acc = {0.f, 0.f, 0.f, 0.f};
#pragma unroll
  for (int kb = 0; kb < 8; kb++){
    v8s a = *(const v8s*)(Arow + kb * 32);
    v8s b = *(const v8s*)(Brow + kb * 32);
    acc = __builtin_amdgcn_mfma_f32_16x16x32_bf16(a, b, acc, 0, 0, 0);
  }
  int n = nt * 16 + lm;                       // 0..2047 gate-row
  int dd = n >> 10, r = n & 1023;
  int cp = row2col(r);
  float bi = bias[n];
#pragma unroll
  for (int r4 = 0; r4 < 4; r4++){
    int t = mt * 16 + lq * 4 + r4;
    U[((size_t)(dd * TT + t)) * 1024 + cp] = f2bf(acc[r4] + bi);
  }
}

// ---------- the recurrent core ----------
// grid=2 (one CU per direction), block=512 (8 waves, 2/SIMD, 256-VGPR budget).
// Each lane owns TWO full gate rows (K=256) sharing the same h-broadcast read:
// the per-CU LDS h-broadcast halves (128 ds_read_b128/step vs 256), which was
// the measured bottleneck (LDS-instr count tracked step time 1:1 in R0).
// rowA = p*256+J (sigmoid: gate i or f), rowB = (p+2)*256+J (tanh g / sigm o).
// Gate exchange: 4 in-wave shuffles; one lgkm-barrier per step; h i8-quantized
// in a 256 B LDS double buffer. Weights: 128 pinned VGPRs of packed i8.

#define Q16(M) M(0) M(1) M(2) M(3) M(4) M(5) M(6) M(7) \
               M(8) M(9) M(10) M(11) M(12) M(13) M(14) M(15)

#define DECLW2(q) unsigned wAx_##q, wAy_##q, wAz_##q, wAw_##q, \
                           wBx_##q, wBy_##q, wBz_##q, wBw_##q;
#define LOADW2(q) { uint4 _ta = WQ4[wbaseA + (q) * 1024]; \
                    wAx_##q = _ta.x; wAy_##q = _ta.y; wAz_##q = _ta.z; wAw_##q = _ta.w; \
                    uint4 _tb = WQ4[wbaseB + (q) * 1024]; \
                    wBx_##q = _tb.x; wBy_##q = _tb.y; wBz_##q = _tb.z; wBw_##q = _tb.w; }
#define PINW2(q) asm volatile("" : "+v"(wAx_##q), "+v"(wAy_##q), "+v"(wAz_##q), "+v"(wAw_##q), \
                                   "+v"(wBx_##q), "+v"(wBy_##q), "+v"(wBz_##q), "+v"(wBw_##q));
// one h read feeds both rows (8 sdot per ds_read_b128)
#define DOTQ2(q, A, B) { uint4 _h = hq[q]; \
  A = SDOT4(wAx_##q, _h.x, A); A = SDOT4(wAy_##q, _h.y, A); \
  A = SDOT4(wAz_##q, _h.z, A); A = SDOT4(wAw_##q, _h.w, A); \
  B = SDOT4(wBx_##q, _h.x, B); B = SDOT4(wBy_##q, _h.y, B); \
  B = SDOT4(wBz_##q, _h.z, B); B = SDOT4(wBw_##q, _h.w, B); }

__global__ void __launch_bounds__(512)
__attribute__((amdgpu_waves_per_eu(2, 2)))
k_lstm9(
    const unsigned short* __restrict__ U, const uint4* __restrict__ WQ4,
    const float* __restrict__ FS, const float* __restrict__ h0,
    const float* __restrict__ c0, unsigned short* __restrict__ hout){
  int d = blockIdx.x;
  int t = threadIdx.x;          // 0..511
  int w = t >> 6;               // wave 0..7
  int l = t & 63;
  int p = l >> 5;               // row-pair selector
  int e = l & 31;
  int J = w * 32 + e;           // hidden element 0..255

  int colA = w * 64 + l;        // storage col of rowA
  int colB = 512 + w * 64 + l;  // storage col of rowB

  __shared__ __align__(16) unsigned char hb[2][256];

  Q16(DECLW2)
  {
    size_t wbaseA = (size_t)d * 16 * 1024 + colA;
    size_t wbaseB = (size_t)d * 16 * 1024 + colB;
    Q16(LOADW2)
  }
  Q16(PINW2)

  float fsA = FS[d * 1024 + colA], fsB = FS[d * 1024 + colB];
  float fsA8 = fsA * (8.f / 127.f), fsA1 = fsA * (1.f / 127.f);
  float fsB8 = fsB * (8.f / 127.f), fsB1 = fsB * (1.f / 127.f);

  // actB constants: p==0 -> tanh (gate g), p==1 -> sigmoid (gate o)
  float CBb = p ? 87.f : 20.f;
  float E0b = p ? -1.f : -2.f;
  float C1b = p ? 0.f  : 1.f;

  float cst = c0[d * 256 + J];  // replicated across p
  if (p == 0){
    float hini = h0[d * 256 + J];
    hini = fminf(fmaxf(hini, -8.f), 8.f);
    hb[0][J] = (unsigned char)(char)(int)rintf(hini * (127.f / 8.f));
  }

  const unsigned short* UpA = U + (size_t)d * TT * 1024 + colA;
  const unsigned short* UpB = U + (size_t)d * TT * 1024 + colB;
  int stp = d ? -1 : 1;
  int tA = d ? TT - 1 : 0;
  unsigned short uA_c = UpA[(size_t)tA * 1024];
  unsigned short uA_n = UpA[(size_t)(tA + stp) * 1024];
  unsigned short uB_c = UpB[(size_t)tA * 1024];
  unsigned short uB_n = UpB[(size_t)(tA + stp) * 1024];

  unsigned short* hp = hout + (size_t)tA * 512 + d * 256 + J;

  __syncthreads();

  for (int s = 0; s < TT; s++){
    int par = s & 1;
    int tt = d ? (TT - 1 - s) : s;
    const uint4* hq = (const uint4*)(&hb[par][0]);   // uniform → broadcast reads

    int a0 = 0, a1 = 0, a2 = 0, a3 = 0;
    int b0 = 0, b1 = 0, b2 = 0, b3 = 0;
    DOTQ2(0,  a0, b0)  DOTQ2(1,  a1, b1)  DOTQ2(2,  a2, b2)  DOTQ2(3,  a3, b3)
    DOTQ2(4,  a0, b0)  DOTQ2(5,  a1, b1)  DOTQ2(6,  a2, b2)  DOTQ2(7,  a3, b3)
    DOTQ2(8,  a0, b0)  DOTQ2(9,  a1, b1)  DOTQ2(10, a2, b2)  DOTQ2(11, a3, b3)
    DOTQ2(12, a0, b0)  DOTQ2(13, a1, b1)  DOTQ2(14, a2, b2)  DOTQ2(15, a3, b3)
    int aA = (a0 + a1) + (a2 + a3);
    int aB = (b0 + b1) + (b2 + b3);

    float fshA = (s == 0) ? fsA8 : fsA1;
    float fshB = (s == 0) ? fsB8 : fsB1;
    float zA = bf2f(uA_c) + (float)aA * fshA;
    float zB = bf2f(uB_c) + (float)aB * fshB;

    // rotate u prefetch (2 steps ahead; clamped always-load)
    uA_c = uA_n; uB_c = uB_n;
    {
      int t2 = tt + 2 * stp;
      t2 = t2 < 0 ? 0 : (t2 > TT - 1 ? TT - 1 : t2);
      uA_n = UpA[(size_t)t2 * 1024];
      uB_n = UpB[(size_t)t2 * 1024];
    }

    // actA: sigmoid (gates i/f)
    float za = fminf(fmaxf(zA, -87.f), 87.f);
    float ea = __expf(-za);
    float actA = __builtin_amdgcn_rcpf(1.f + ea);
    // actB: tanh (p==0, gate g) or sigmoid (p==1, gate o)
    float zb = fminf(fmaxf(zB, -CBb), CBb);
    float eb = __expf(E0b * zb);
    float actB = fmaf(-C1b, eb, 1.f) * __builtin_amdgcn_rcpf(1.f + eb);

    // in-wave gather of the 4 gate activations for element J
    float gi = __shfl(actA, e,      64);
    float gf = __shfl(actA, e + 32, 64);
    float gg = __shfl(actB, e,      64);
    float go = __shfl(actB, e + 32, 64);

    cst = fmaf(gf, cst, gi * gg);
    float cc = fminf(fmaxf(cst, -20.f), 20.f);
    float e2 = __expf(-2.f * cc);
    float th = (1.f - e2) * __builtin_amdgcn_rcpf(1.f + e2);
    float h = go * th;

    if (p == 0){
      int qv = (int)rintf(fminf(fmaxf(h, -1.f), 1.f) * 127.f);
      hb[par ^ 1][J] = (unsigned char)(char)qv;     // 32 B contiguous per wave
    } else {
      *hp = f2bf(h);                                // 64 B contiguous per wave
    }
    hp += stp * 512;

    BARRIER_LDS();
  }
}

// feats via MFMA: FE[t][j] = HOUT[t]·WOP[j] + bout[j], WOP padded to 32 rows
__global__ void k_feats2(const unsigned short* __restrict__ HOUT,
                         const unsigned short* __restrict__ WOP,
                         const float* __restrict__ bout,
                         float* __restrict__ feats){
  int wave = threadIdx.x >> 6, l = threadIdx.x & 63;
  int tile = blockIdx.x * 4 + wave;           // 0..511
  int mt = tile & 255, nt = tile >> 8;        // 256 M-tiles x 2 N-tiles
  int lm = l & 15, lq = l >> 4;
  const unsigned short* Arow = HOUT + (size_t)(mt * 16 + lm) * 512 + lq * 8;
  const unsigned short* Brow = WOP  + (size_t)(nt * 16 + lm) * 512 + lq * 8;
  v4f acc = {0.f, 0.f, 0.f, 0.f};
#pragma unroll
  for (int kb = 0; kb < 16; kb++){
    v8s a = *(const v8s*)(Arow + kb * 32);
    v8s b = *(const v8s*)(Brow + kb * 32);
    acc = __builtin_amdgcn_mfma_f32_16x16x32_bf16(a, b, acc, 0, 0, 0);
  }
  int n = nt * 16 + lm;
  if (n < LL){
    float bi = bout[n];
#pragma unroll
    for (int r4 = 0; r4 < 4; r4++){
      int t = mt * 16 + lq * 4 + r4;
      feats[t * LL + n] = acc[r4] + bi;
    }
  }
}

// V1: per-chunk max-plus matrix product
__global__ void k_vchunk(const float* __restrict__ feats, const float* __restrict__ trans,
                         float* __restrict__ P){
  int c = blockIdx.x, j = threadIdx.x;
  __shared__ float Ps[2][LL][LL];
  bool act = j < LL;
  float trow[LL];
  if (act){
#pragma unroll
    for (int i = 0; i < LL; i++) trow[i] = trans[j * LL + i];
    for (int i = 0; i < LL; i++) Ps[0][i][j] = (i == j) ? 0.f : -1e30f;
  }
  __syncthreads();
  for (int s = 0; s < 16; s++){
    int t = c * 16 + s;
    int pb = s & 1;
    if (act){
      float fj = feats[t * LL + j];
      for (int i = 0; i < LL; i++){
        float m = Ps[pb][i][0] + trow[0];
#pragma unroll
        for (int mm = 1; mm < LL; mm++) m = fmaxf(m, Ps[pb][i][mm] + trow[mm]);
        Ps[pb ^ 1][i][j] = m + fj;
      }
    }
    __syncthreads();
  }
  if (act)
    for (int i = 0; i < LL; i++) P[((size_t)c * LL + i) * LL + j] = Ps[0][i][j];
}

// V2: sequential boundary-alpha scan (prefetch-pipelined)
__global__ void k_vscan(const float* __restrict__ P, float* __restrict__ bal){
  int tid = threadIdx.x;
  bool act = tid < LL;
  __shared__ float al[LL];
  __shared__ float Pl[400];
  if (act){
    float a = (tid == STARTT) ? 0.f : NEGV;
    al[tid] = a;
    bal[tid] = a;
  }
  for (int k = tid; k < 400; k += 64) Pl[k] = P[k];
  __syncthreads();
  for (int c = 0; c < NCH; c++){
    float p0 = 0.f, p1 = 0.f, p2 = 0.f, p3 = 0.f, p4 = 0.f, p5 = 0.f, p6 = 0.f;
    if (c + 1 < NCH){
      const float* Pn = P + (size_t)(c + 1) * 400;
      p0 = Pn[tid];        p1 = Pn[tid + 64];  p2 = Pn[tid + 128];
      p3 = Pn[tid + 192];  p4 = Pn[tid + 256]; p5 = Pn[tid + 320];
      if (tid + 384 < 400) p6 = Pn[tid + 384];
    }
    float m = -1e30f;
    if (act){
      m = al[0] + Pl[tid];
#pragma unroll
      for (int i = 1; i < LL; i++) m = fmaxf(m, al[i] + Pl[i * LL + tid]);
    }
    __syncthreads();
    if (act){
      al[tid] = m;
      bal[(c + 1) * LL + tid] = m;
    }
    if (c + 1 < NCH){
      Pl[tid] = p0;        Pl[tid + 64] = p1;  Pl[tid + 128] = p2;
      Pl[tid + 192] = p3;  Pl[tid + 256] = p4; Pl[tid + 320] = p5;
      if (tid + 384 < 400) Pl[tid + 384] = p6;
    }
    __syncthreads();
  }
}

// V3: per-chunk backpointers + chunk backtrace map
__global__ void k_vbp(const float* __restrict__ feats, const float* __restrict__ trans,
                      const float* __restrict__ bal, unsigned char* __restrict__ bp,
                      unsigned char* __restrict__ M){
  int c = blockIdx.x, j = threadIdx.x;
  bool act = j < LL;
  __shared__ float al[2][LL];
  __shared__ unsigned char bpl[16][LL];
  float trow[LL];
  if (act){
#pragma unroll
    for (int i = 0; i < LL; i++) trow[i] = trans[j * LL + i];
    al[0][j] = bal[c * LL + j];
  }
  __syncthreads();
  for (int s = 0; s < 16; s++){
    int t = c * 16 + s;
    int pb = s & 1;
    if (act){
      float m = al[pb][0] + trow[0];
      int arg = 0;
#pragma unroll
      for (int i = 1; i < LL; i++){
        float v = al[pb][i] + trow[i];
        if (v > m){ m = v; arg = i; }
      }
      bpl[s][j] = (unsigned char)arg;
      bp[(size_t)t * LL + j] = (unsigned char)arg;
      al[pb ^ 1][j] = m + feats[t * LL + j];
    }
    __syncthreads();
  }
  if (act){
    int tag = j;
    for (int s = 15; s >= 0; s--) tag = bpl[s][tag];
    M[c * LL + j] = (unsigned char)tag;
  }
}

// V4: final score + chunk-boundary tag chase
__global__ void k_vtag(const float* __restrict__ bal, const float* __restrict__ trans,
                       const unsigned char* __restrict__ M, int* __restrict__ Eg,
                       float* __restrict__ out){
  int tid = threadIdx.x;
  __shared__ unsigned char Ml[NCH * LL];
  __shared__ float fin[LL];
  for (int k = tid; k < NCH * LL; k += 64) Ml[k] = M[k];
  if (tid < LL) fin[tid] = bal[NCH * LL + tid] + trans[STOPP * LL + tid];
  __syncthreads();
  if (tid == 0){
    float m = fin[0]; int arg = 0;
    for (int i = 1; i < LL; i++) if (fin[i] > m){ m = fin[i]; arg = i; }
    out[0] = m;
    int tag = arg;
    Eg[NCH - 1] = tag;
    for (int c = NCH - 1; c >= 1; c--){
      tag = Ml[c * LL + tag];
      Eg[c - 1] = tag;
    }
  }
}

// V5: parallel path emission
__global__ void k_vemit(const int* __restrict__ Eg, const unsigned char* __restrict__ bp,
                        float* __restrict__ out){
  int c = threadIdx.x;
  int tag = Eg[c];
  out[1 + c * 16 + 15] = (float)tag;
  for (int s = 15; s >= 1; s--){
    tag = bp[(size_t)(c * 16 + s) * LL + tag];
    out[1 + c * 16 + s - 1] = (float)tag;
  }
}

// ---------- launcher ----------
extern "C" void kernel_launch(void* const* d_in, const int* in_sizes, int n_in,
                              void* d_out, int out_size, void* d_ws, size_t ws_size,
                              hipStream_t stream){
  (void)in_sizes; (void)n_in; (void)out_size; (void)ws_size;
  const int*   x     = (const int*)d_in[0];
  const float* emb   = (const float*)d_in[1];
  const float* wihf  = (const float*)d_in[2];
  const float* whhf  = (const float*)d_in[3];
  const float* bihf  = (const float*)d_in[4];
  const float* bhhf  = (const float*)d_in[5];
  const float* wihb  = (const float*)d_in[6];
  const float* whhb  = (const float*)d_in[7];
  const float* bihb  = (const float*)d_in[8];
  const float* bhhb  = (const float*)d_in[9];
  const float* wout  = (const float*)d_in[10];
  const float* bout  = (const float*)d_in[11];
  const float* trans = (const float*)d_in[12];
  const float* h0    = (const float*)d_in[13];
  const float* c0    = (const float*)d_in[14];
  float* out = (float*)d_out;
  char* ws = (char*)d_ws;

  unsigned short* U    = (unsigned short*)(ws + OFF_U);
  unsigned short* X    = (unsigned short*)(ws + OFF_X);
  unsigned short* WIH  = (unsigned short*)(ws + OFF_WIH);
  float*          BIAS = (float*)(ws + OFF_BIAS);
  unsigned int*   WQ   = (unsigned int*)(ws + OFF_WQ);
  float*          FS   = (float*)(ws + OFF_FS);
  unsigned short* WOP  = (unsigned short*)(ws + OFF_WOP);
  unsigned short* HOUT = (unsigned short*)(ws + OFF_HOUT);
  float*          FE   = (float*)(ws + OFF_FE);
  float*          P    = (float*)(ws + OFF_P);
  float*          BAL  = (float*)(ws + OFF_BAL);
  unsigned char*  BP   = (unsigned char*)(ws + OFF_BP);
  unsigned char*  M    = (unsigned char*)(ws + OFF_M);
  int*            EG   = (int*)(ws + OFF_EG);

  k_gather<<<TT, 64, 0, stream>>>(x, emb, X);
  k_wih<<<256, 256, 0, stream>>>(wihf, wihb, WIH);
  k_bias<<<8, 256, 0, stream>>>(bihf, bhhf, bihb, bhhb, BIAS);
  k_wout<<<64, 256, 0, stream>>>(wout, WOP);
  k_whh5<<<2048, 64, 0, stream>>>(whhf, whhb, WQ, FS);
  k_gemm_u<<<8192, 256, 0, stream>>>(X, WIH, BIAS, U);
  k_lstm9<<<2, 512, 0, stream>>>(U, (const uint4*)WQ, FS, h0, c0, HOUT);
  k_feats2<<<128, 256, 0, stream>>>(HOUT, WOP, bout, FE);
  k_vchunk<<<NCH, 64, 0, stream>>>(FE, trans, P);
  k_vscan<<<1, 64, 0, stream>>>(P, BAL);
  k_vbp<<<NCH, 64, 0, stream>>>(FE, trans, BAL, BP, M);
  k_vtag<<<1, 64, 0, stream>>>(BAL, trans, M, EG, out);
  k_vemit<<<1, 256, 0, stream>>>(EG, BP, out);
}

// Round 3
// 4236.369 us; speedup vs baseline: 1.1484x; 1.0447x over previous
//
#include <hip/hip_runtime.h>
#include <hip/hip_bf16.h>
#include <stdint.h>

#define TT 4096
#define EE 256
#define LL 20
#define STARTT 18
#define STOPP 19
#define NEGV -10000.0f
#define NCH 256   // TT/16

typedef short v8s __attribute__((ext_vector_type(8)));
typedef float v4f __attribute__((ext_vector_type(4)));

// ---------- helpers ----------
__device__ inline float bf2f(unsigned short u){
  unsigned int x = ((unsigned int)u) << 16;
  return __builtin_bit_cast(float, x);
}
__device__ inline unsigned short f2bf(float f){
  unsigned int x = __builtin_bit_cast(unsigned int, f);
  unsigned int r = (x + 0x7FFFu + ((x >> 16) & 1u)) >> 16;
  return (unsigned short)r;
}

#if __has_builtin(__builtin_amdgcn_sdot4)
#define SDOT4(a,b,c) __builtin_amdgcn_sdot4((int)(a),(int)(b),(c),false)
#else
__device__ inline int sdot4_sw(int a, int b, int c){
  return c + (int)(char)(a)        * (int)(char)(b)
           + (int)(char)(a >> 8)   * (int)(char)(b >> 8)
           + (int)(char)(a >> 16)  * (int)(char)(b >> 16)
           + (int)(char)(a >> 24)  * (int)(char)(b >> 24);
}
#define SDOT4(a,b,c) sdot4_sw((int)(a),(int)(b),(c))
#endif

// lgkm-only barrier: syncs LDS without draining outstanding global (vmcnt) prefetch
#define BARRIER_LDS() asm volatile("s_waitcnt lgkmcnt(0)\ns_barrier" ::: "memory")

// ---------- workspace layout (bytes) ----------
constexpr size_t OFF_U    = 0;                              // bf16 [2][T][256][4] (elem-major, 4 gates packed)
constexpr size_t SZ_U     = 2ull*TT*1024*2;
constexpr size_t OFF_X    = OFF_U + SZ_U;                   // bf16 [T][E]
constexpr size_t SZ_X     = (size_t)TT*EE*2;
constexpr size_t OFF_WIH  = OFF_X + SZ_X;                   // bf16 [2048][256]
constexpr size_t SZ_WIH   = 2048ull*256*2;
constexpr size_t OFF_BIAS = OFF_WIH + SZ_WIH;               // f32 [2048]
constexpr size_t SZ_BIAS  = 2048ull*4;
constexpr size_t OFF_WQ   = OFF_BIAS + SZ_BIAS;             // uint4 [2][32][512] (i8 packed, K-split layout)
constexpr size_t SZ_WQ    = 2ull*32*512*16;
constexpr size_t OFF_FS   = OFF_WQ + SZ_WQ;                 // float4 [2][256] (per-elem 4 gate scales)
constexpr size_t SZ_FS    = 2ull*256*16;
constexpr size_t OFF_WOP  = OFF_FS + SZ_FS;                 // bf16 [32][512]
constexpr size_t SZ_WOP   = 32ull*512*2;
constexpr size_t OFF_HOUT = OFF_WOP + SZ_WOP;               // bf16 [T][512]
constexpr size_t SZ_HOUT  = (size_t)TT*512*2;
constexpr size_t OFF_FE   = OFF_HOUT + SZ_HOUT;             // f32 [T][20]
constexpr size_t SZ_FE    = (size_t)TT*LL*4;
constexpr size_t OFF_P    = OFF_FE + SZ_FE;                 // f32 [256][20][20]
constexpr size_t SZ_P     = 256ull*400*4;
constexpr size_t OFF_BAL  = OFF_P + SZ_P;                   // f32 [257][20]
constexpr size_t SZ_BAL   = 20736;
constexpr size_t OFF_BP   = OFF_BAL + SZ_BAL;               // u8 [T][20]
constexpr size_t SZ_BP    = (size_t)TT*LL;
constexpr size_t OFF_M    = OFF_BP + SZ_BP;                 // u8 [256][20]
constexpr size_t SZ_M     = 256ull*LL;
constexpr size_t OFF_EG   = OFF_M + SZ_M + 64;              // i32 [256]

// ---------- prep kernels ----------

__global__ void k_gather(const int* __restrict__ x, const float* __restrict__ emb,
                         unsigned short* __restrict__ X){
  int t = blockIdx.x;
  int xt = x[t];
  const float4* src = (const float4*)(emb + (size_t)xt * EE);
  float4 v = src[threadIdx.x];
  ushort4 o;
  o.x = f2bf(v.x); o.y = f2bf(v.y); o.z = f2bf(v.z); o.w = f2bf(v.w);
  ((ushort4*)(X + (size_t)t * EE))[threadIdx.x] = o;
}

__global__ void k_wih(const float* __restrict__ wf, const float* __restrict__ wb,
                      unsigned short* __restrict__ WIH){
  int gid = blockIdx.x * 256 + threadIdx.x;   // 65536
  int row = gid >> 5, c8 = gid & 31;
  const float* src = (row < 1024 ? wf + (size_t)row * EE : wb + (size_t)(row - 1024) * EE) + c8 * 8;
  unsigned short* dst = WIH + (size_t)row * 256 + c8 * 8;
#pragma unroll
  for (int i = 0; i < 8; i++) dst[i] = f2bf(src[i]);
}

__global__ void k_bias(const float* bf, const float* hf, const float* bb, const float* hb,
                       float* __restrict__ bias){
  int i = blockIdx.x * 256 + threadIdx.x;     // 2048
  int r = i & 1023;
  bias[i] = (i < 1024) ? (bf[r] + hf[r]) : (bb[r] + hb[r]);
}

// w_out -> bf16, padded to 32 rows
__global__ void k_wout(const float* __restrict__ wout, unsigned short* __restrict__ WOP){
  int gid = blockIdx.x * 256 + threadIdx.x;   // 16384 = 32*512
  int row = gid >> 9, k = gid & 511;
  WOP[gid] = (row < LL) ? f2bf(wout[row * 512 + k]) : 0;
}

// quantize W_hh rows to int8 with per-row scale, K-split layout.
// Core thread tid (0..511) = w*64 + half*32 + e owns element J=w*32+e, K-half 'half',
// all 4 gate rows. WQ quad index q = g*8 + kq (kq: 16-byte group within the half).
// WQ[(d*32+q)*512 + tid] (uint4). FS float4[d*256+J] = per-gate scales (x=i,y=f,z=g,w=o).
__global__ void k_whh6(const float* __restrict__ whf, const float* __restrict__ whb,
                       unsigned int* __restrict__ WQ, float* __restrict__ FS){
  int row = blockIdx.x;       // 0..2047
  int d = row >> 10, R = row & 1023;
  int g = R >> 8, J = R & 255;
  const float* W = (d ? whb : whf) + (size_t)R * 256;
  int t = threadIdx.x;        // 0..63 ; covers cols 4t..4t+3
  float4 v = ((const float4*)W)[t];
  float m = fmaxf(fmaxf(fabsf(v.x), fabsf(v.y)), fmaxf(fabsf(v.z), fabsf(v.w)));
#pragma unroll
  for (int o = 32; o >= 1; o >>= 1) m = fmaxf(m, __shfl_down(m, o));
  m = __shfl(m, 0);
  float sc = (m > 0.f) ? (m / 127.f) : 1.f;
  float inv = 1.f / sc;
  int a = (int)rintf(v.x * inv), b = (int)rintf(v.y * inv);
  int c = (int)rintf(v.z * inv), e4 = (int)rintf(v.w * inv);
  unsigned int pack = ((unsigned)a & 255u) | (((unsigned)b & 255u) << 8)
                    | (((unsigned)c & 255u) << 16) | (((unsigned)e4 & 255u) << 24);
  int half = t >> 5;          // k = 4t: k>=128 <=> t>=32
  int kq = (t >> 2) & 7;      // 16-byte group within half
  int comp = t & 3;
  int tid = (J >> 5) * 64 + half * 32 + (J & 31);
  int q = g * 8 + kq;
  WQ[(((size_t)(d * 32 + q)) * 512 + tid) * 4 + comp] = pack;
  if (t == 0) FS[((size_t)d * 256 + J) * 4 + g] = sc;
}

// U[d][t][J][g] = bf16( X[t]·W_ih row (g*256+J) + bias )  via 16x16x32 bf16 MFMA
__global__ void k_gemm_u(const unsigned short* __restrict__ X,
                         const unsigned short* __restrict__ WIH,
                         const float* __restrict__ bias,
                         unsigned short* __restrict__ U){
  int wave = threadIdx.x >> 6, l = threadIdx.x & 63;
  int tile = blockIdx.x * 4 + wave;           // 0..32767
  int mt = tile & 255, nt = tile >> 8;        // 256 x 128 tiles
  int lm = l & 15, lq = l >> 4;
  const unsigned short* Arow = X   + (size_t)(mt * 16 + lm) * 256 + lq * 8;
  const unsigned short* Brow = WIH + (size_t)(nt * 16 + lm) * 256 + lq * 8;
  v4f acc = {0.f, 0.f, 0.f, 0.f};
#pragma unroll
  for (int kb = 0; kb < 8; kb++){
    v8s a = *(const v8s*)(Arow + kb * 32);
    v8s b = *(const v8s*)(Brow + kb * 32);
    acc = __builtin_amdgcn_mfma_f32_16x16x32_bf16(a, b, acc, 0, 0, 0);
  }
  int n = nt * 16 + lm;                       // 0..2047 gate-row
  int dd = n >> 10, r = n & 1023;
  int g = r >> 8, J = r & 255;
  float bi = bias[n];
#pragma unroll
  for (int r4 = 0; r4 < 4; r4++){
    int t = mt * 16 + lq * 4 + r4;
    U[(((size_t)(dd * TT + t)) * 256 + J) * 4 + g] = f2bf(acc[r4] + bi);
  }
}

// ---------- the recurrent core ----------
// grid=2 (one CU per direction), block=512 (8 waves, 2/SIMD, 256-VGPR arch budget).
// K-SPLIT mapping: lane l of wave w: half=l>>5, e=l&31, J=w*32+e. Lane owns all 4
// gate rows of element J restricted to K in [half*128, half*128+128): 128 weight u32.
// Max live set ~ 128 w + 32 hq + ~60 working < 256 arch VGPRs -> no AGPR demotion,
// no v_accvgpr_read copies (R1's measured 185-instr/step overhead).
// Gate combine: 4 integer __shfl_xor(.,32) partial-sum adds (exact). All 4 gates are
// lane-local afterwards -> no bpermute gather, no divergent gate constants.
// h: i8 LDS double buffer (256 B); one lgkm barrier per step; U: one uint2/step.

#define K8(M) M(0) M(1) M(2) M(3) M(4) M(5) M(6) M(7)

#define DECLW(k) unsigned w0x_##k,w0y_##k,w0z_##k,w0w_##k, \
                          w1x_##k,w1y_##k,w1z_##k,w1w_##k, \
                          w2x_##k,w2y_##k,w2z_##k,w2w_##k, \
                          w3x_##k,w3y_##k,w3z_##k,w3w_##k;
#define LOADW(k) { uint4 _t0 = WQ4[wb + (size_t)((k)      ) * 512]; \
                   w0x_##k=_t0.x; w0y_##k=_t0.y; w0z_##k=_t0.z; w0w_##k=_t0.w; \
                   uint4 _t1 = WQ4[wb + (size_t)((k) +  8 ) * 512]; \
                   w1x_##k=_t1.x; w1y_##k=_t1.y; w1z_##k=_t1.z; w1w_##k=_t1.w; \
                   uint4 _t2 = WQ4[wb + (size_t)((k) + 16 ) * 512]; \
                   w2x_##k=_t2.x; w2y_##k=_t2.y; w2z_##k=_t2.z; w2w_##k=_t2.w; \
                   uint4 _t3 = WQ4[wb + (size_t)((k) + 24 ) * 512]; \
                   w3x_##k=_t3.x; w3y_##k=_t3.y; w3z_##k=_t3.z; w3w_##k=_t3.w; }
#define PINW(k) asm volatile("" : "+v"(w0x_##k), "+v"(w0y_##k), "+v"(w0z_##k), "+v"(w0w_##k), \
                                  "+v"(w1x_##k), "+v"(w1y_##k), "+v"(w1z_##k), "+v"(w1w_##k), \
                                  "+v"(w2x_##k), "+v"(w2y_##k), "+v"(w2z_##k), "+v"(w2w_##k), \
                                  "+v"(w3x_##k), "+v"(w3y_##k), "+v"(w3z_##k), "+v"(w3w_##k));
#define DOTK(k) { uint4 _h = hq[k]; \
  a0 = SDOT4(w0x_##k,_h.x,a0); a0 = SDOT4(w0y_##k,_h.y,a0); \
  a0 = SDOT4(w0z_##k,_h.z,a0); a0 = SDOT4(w0w_##k,_h.w,a0); \
  a1 = SDOT4(w1x_##k,_h.x,a1); a1 = SDOT4(w1y_##k,_h.y,a1); \
  a1 = SDOT4(w1z_##k,_h.z,a1); a1 = SDOT4(w1w_##k,_h.w,a1); \
  a2 = SDOT4(w2x_##k,_h.x,a2); a2 = SDOT4(w2y_##k,_h.y,a2); \
  a2 = SDOT4(w2z_##k,_h.z,a2); a2 = SDOT4(w2w_##k,_h.w,a2); \
  a3 = SDOT4(w3x_##k,_h.x,a3); a3 = SDOT4(w3y_##k,_h.y,a3); \
  a3 = SDOT4(w3z_##k,_h.z,a3); a3 = SDOT4(w3w_##k,_h.w,a3); }

__global__ void __launch_bounds__(512)
__attribute__((amdgpu_waves_per_eu(2, 2)))
k_lstm10(
    const unsigned short* __restrict__ U, const uint4* __restrict__ WQ4,
    const float4* __restrict__ FS4, const float* __restrict__ h0,
    const float* __restrict__ c0, unsigned short* __restrict__ hout){
  int d = blockIdx.x;
  int tid = threadIdx.x;        // 0..511
  int w = tid >> 6;
  int l = tid & 63;
  int half = l >> 5;
  int e = l & 31;
  int J = w * 32 + e;           // hidden element (replicated across halves)

  __shared__ __align__(16) unsigned char hb[2][256];

  K8(DECLW)
  {
    size_t wb = (size_t)d * 16384 + tid;      // uint4 units; quad q at wb + q*512
    K8(LOADW)
  }
  K8(PINW)

  float4 fsv = FS4[(size_t)d * 256 + J];      // per-gate scales (i,f,g,o)

  float cst = c0[d * 256 + J];
  if (half == 0){
    float hini = h0[d * 256 + J];
    hini = fminf(fmaxf(hini, -8.f), 8.f);
    hb[0][J] = (unsigned char)(char)(int)rintf(hini * (127.f / 8.f));
  }

  const unsigned short* Up0 = U + (size_t)d * TT * 1024 + (size_t)J * 4;
  int stp = d ? -1 : 1;
  int tA = d ? TT - 1 : 0;
  uint2 u_c = *(const uint2*)(Up0 + (size_t)tA * 1024);
  uint2 u_n = *(const uint2*)(Up0 + (size_t)(tA + stp) * 1024);

  unsigned short* hp = hout + (size_t)tA * 512 + d * 256 + J;

  __syncthreads();

  for (int s = 0; s < TT; s++){
    int par = s & 1;
    int tt = d ? (TT - 1 - s) : s;
    const uint4* hq = (const uint4*)(&hb[par][half * 128]);  // 2 addrs/wave: free

    int a0 = 0, a1 = 0, a2 = 0, a3 = 0;
    K8(DOTK)                       // 128 x v_dot4_i32_i8

    // combine K-halves (integer-exact)
    a0 += __shfl_xor(a0, 32);
    a1 += __shfl_xor(a1, 32);
    a2 += __shfl_xor(a2, 32);
    a3 += __shfl_xor(a3, 32);

    float m1 = (s == 0) ? (8.f / 127.f) : (1.f / 127.f);
    float u_i = bf2f((unsigned short)(u_c.x & 0xffffu));
    float u_f = bf2f((unsigned short)(u_c.x >> 16));
    float u_g = bf2f((unsigned short)(u_c.y & 0xffffu));
    float u_o = bf2f((unsigned short)(u_c.y >> 16));
    float zi = u_i + (float)a0 * (fsv.x * m1);
    float zf = u_f + (float)a1 * (fsv.y * m1);
    float zg = u_g + (float)a2 * (fsv.z * m1);
    float zo = u_o + (float)a3 * (fsv.w * m1);

    // rotate u prefetch (2 steps ahead; clamped always-load)
    u_c = u_n;
    {
      int t2 = tt + 2 * stp;
      t2 = t2 < 0 ? 0 : (t2 > TT - 1 ? TT - 1 : t2);
      u_n = *(const uint2*)(Up0 + (size_t)t2 * 1024);
    }

    // activations (all lanes, all 4 gates local)
    float za = fminf(fmaxf(zi, -87.f), 87.f);
    float ea = __expf(-za);
    float gi = __builtin_amdgcn_rcpf(1.f + ea);
    float zb = fminf(fmaxf(zf, -87.f), 87.f);
    float eb = __expf(-zb);
    float gf = __builtin_amdgcn_rcpf(1.f + eb);
    float zc = fminf(fmaxf(zg, -20.f), 20.f);
    float ec = __expf(-2.f * zc);
    float gg = (1.f - ec) * __builtin_amdgcn_rcpf(1.f + ec);
    float zd = fminf(fmaxf(zo, -87.f), 87.f);
    float ed = __expf(-zd);
    float go = __builtin_amdgcn_rcpf(1.f + ed);

    cst = fmaf(gf, cst, gi * gg);
    float cc = fminf(fmaxf(cst, -20.f), 20.f);
    float e2 = __expf(-2.f * cc);
    float th = (1.f - e2) * __builtin_amdgcn_rcpf(1.f + e2);
    float h = go * th;

    if (half == 0){
      int qv = (int)rintf(fminf(fmaxf(h, -1.f), 1.f) * 127.f);
      hb[par ^ 1][J] = (unsigned char)(char)qv;   // 32 B contiguous per wave
    } else {
      *hp = f2bf(h);                              // 64 B contiguous per wave
    }
    hp += stp * 512;

    BARRIER_LDS();
  }
}

// feats via MFMA: FE[t][j] = HOUT[t]·WOP[j] + bout[j], WOP padded to 32 rows
__global__ void k_feats2(const unsigned short* __restrict__ HOUT,
                         const unsigned short* __restrict__ WOP,
                         const float* __restrict__ bout,
                         float* __restrict__ feats){
  int wave = threadIdx.x >> 6, l = threadIdx.x & 63;
  int tile = blockIdx.x * 4 + wave;           // 0..511
  int mt = tile & 255, nt = tile >> 8;        // 256 M-tiles x 2 N-tiles
  int lm = l & 15, lq = l >> 4;
  const unsigned short* Arow = HOUT + (size_t)(mt * 16 + lm) * 512 + lq * 8;
  const unsigned short* Brow = WOP  + (size_t)(nt * 16 + lm) * 512 + lq * 8;
  v4f acc = {0.f, 0.f, 0.f, 0.f};
#pragma unroll
  for (int kb = 0; kb < 16; kb++){
    v8s a = *(const v8s*)(Arow + kb * 32);
    v8s b = *(const v8s*)(Brow + kb * 32);
    acc = __builtin_amdgcn_mfma_f32_16x16x32_bf16(a, b, acc, 0, 0, 0);
  }
  int n = nt * 16 + lm;
  if (n < LL){
    float bi = bout[n];
#pragma unroll
    for (int r4 = 0; r4 < 4; r4++){
      int t = mt * 16 + lq * 4 + r4;
      feats[t * LL + n] = acc[r4] + bi;
    }
  }
}

// V1: per-chunk max-plus matrix product
__global__ void k_vchunk(const float* __restrict__ feats, const float* __restrict__ trans,
                         float* __restrict__ P){
  int c = blockIdx.x, j = threadIdx.x;
  __shared__ float Ps[2][LL][LL];
  bool act = j < LL;
  float trow[LL];
  if (act){
#pragma unroll
    for (int i = 0; i < LL; i++) trow[i] = trans[j * LL + i];
    for (int i = 0; i < LL; i++) Ps[0][i][j] = (i == j) ? 0.f : -1e30f;
  }
  __syncthreads();
  for (int s = 0; s < 16; s++){
    int t = c * 16 + s;
    int pb = s & 1;
    if (act){
      float fj = feats[t * LL + j];
      for (int i = 0; i < LL; i++){
        float m = Ps[pb][i][0] + trow[0];
#pragma unroll
        for (int mm = 1; mm < LL; mm++) m = fmaxf(m, Ps[pb][i][mm] + trow[mm]);
        Ps[pb ^ 1][i][j] = m + fj;
      }
    }
    __syncthreads();
  }
  if (act)
    for (int i = 0; i < LL; i++) P[((size_t)c * LL + i) * LL + j] = Ps[0][i][j];
}

// V2: sequential boundary-alpha scan (prefetch-pipelined)
__global__ void k_vscan(const float* __restrict__ P, float* __restrict__ bal){
  int tid = threadIdx.x;
  bool act = tid < LL;
  __shared__ float al[LL];
  __shared__ float Pl[400];
  if (act){
    float a = (tid == STARTT) ? 0.f : NEGV;
    al[tid] = a;
    bal[tid] = a;
  }
  for (int k = tid; k < 400; k += 64) Pl[k] = P[k];
  __syncthreads();
  for (int c = 0; c < NCH; c++){
    float p0 = 0.f, p1 = 0.f, p2 = 0.f, p3 = 0.f, p4 = 0.f, p5 = 0.f, p6 = 0.f;
    if (c + 1 < NCH){
      const float* Pn = P + (size_t)(c + 1) * 400;
      p0 = Pn[tid];        p1 = Pn[tid + 64];  p2 = Pn[tid + 128];
      p3 = Pn[tid + 192];  p4 = Pn[tid + 256]; p5 = Pn[tid + 320];
      if (tid + 384 < 400) p6 = Pn[tid + 384];
    }
    float m = -1e30f;
    if (act){
      m = al[0] + Pl[tid];
#pragma unroll
      for (int i = 1; i < LL; i++) m = fmaxf(m, al[i] + Pl[i * LL + tid]);
    }
    __syncthreads();
    if (act){
      al[tid] = m;
      bal[(c + 1) * LL + tid] = m;
    }
    if (c + 1 < NCH){
      Pl[tid] = p0;        Pl[tid + 64] = p1;  Pl[tid + 128] = p2;
      Pl[tid + 192] = p3;  Pl[tid + 256] = p4; Pl[tid + 320] = p5;
      if (tid + 384 < 400) Pl[tid + 384] = p6;
    }
    __syncthreads();
  }
}

// V3: per-chunk backpointers + chunk backtrace map
__global__ void k_vbp(const float* __restrict__ feats, const float* __restrict__ trans,
                      const float* __restrict__ bal, unsigned char* __restrict__ bp,
                      unsigned char* __restrict__ M){
  int c = blockIdx.x, j = threadIdx.x;
  bool act = j < LL;
  __shared__ float al[2][LL];
  __shared__ unsigned char bpl[16][LL];
  float trow[LL];
  if (act){
#pragma unroll
    for (int i = 0; i < LL; i++) trow[i] = trans[j * LL + i];
    al[0][j] = bal[c * LL + j];
  }
  __syncthreads();
  for (int s = 0; s < 16; s++){
    int t = c * 16 + s;
    int pb = s & 1;
    if (act){
      float m = al[pb][0] + trow[0];
      int arg = 0;
#pragma unroll
      for (int i = 1; i < LL; i++){
        float v = al[pb][i] + trow[i];
        if (v > m){ m = v; arg = i; }
      }
      bpl[s][j] = (unsigned char)arg;
      bp[(size_t)t * LL + j] = (unsigned char)arg;
      al[pb ^ 1][j] = m + feats[t * LL + j];
    }
    __syncthreads();
  }
  if (act){
    int tag = j;
    for (int s = 15; s >= 0; s--) tag = bpl[s][tag];
    M[c * LL + j] = (unsigned char)tag;
  }
}

// V4: final score + chunk-boundary tag chase
__global__ void k_vtag(const float* __restrict__ bal, const float* __restrict__ trans,
                       const unsigned char* __restrict__ M, int* __restrict__ Eg,
                       float* __restrict__ out){
  int tid = threadIdx.x;
  __shared__ unsigned char Ml[NCH * LL];
  __shared__ float fin[LL];
  for (int k = tid; k < NCH * LL; k += 64) Ml[k] = M[k];
  if (tid < LL) fin[tid] = bal[NCH * LL + tid] + trans[STOPP * LL + tid];
  __syncthreads();
  if (tid == 0){
    float m = fin[0]; int arg = 0;
    for (int i = 1; i < LL; i++) if (fin[i] > m){ m = fin[i]; arg = i; }
    out[0] = m;
    int tag = arg;
    Eg[NCH - 1] = tag;
    for (int c = NCH - 1; c >= 1; c--){
      tag = Ml[c * LL + tag];
      Eg[c - 1] = tag;
    }
  }
}

// V5: parallel path emission
__global__ void k_vemit(const int* __restrict__ Eg, const unsigned char* __restrict__ bp,
                        float* __restrict__ out){
  int c = threadIdx.x;
  int tag = Eg[c];
  out[1 + c * 16 + 15] = (float)tag;
  for (int s = 15; s >= 1; s--){
    tag = bp[(size_t)(c * 16 + s) * LL + tag];
    out[1 + c * 16 + s - 1] = (float)tag;
  }
}

// ---------- launcher ----------
extern "C" void kernel_launch(void* const* d_in, const int* in_sizes, int n_in,
                              void* d_out, int out_size, void* d_ws, size_t ws_size,
                              hipStream_t stream){
  (void)in_sizes; (void)n_in; (void)out_size; (void)ws_size;
  const int*   x     = (const int*)d_in[0];
  const float* emb   = (const float*)d_in[1];
  const float* wihf  = (const float*)d_in[2];
  const float* whhf  = (const float*)d_in[3];
  const float* bihf  = (const float*)d_in[4];
  const float* bhhf  = (const float*)d_in[5];
  const float* wihb  = (const float*)d_in[6];
  const float* whhb  = (const float*)d_in[7];
  const float* bihb  = (const float*)d_in[8];
  const float* bhhb  = (const float*)d_in[9];
  const float* wout  = (const float*)d_in[10];
  const float* bout  = (const float*)d_in[11];
  const float* trans = (const float*)d_in[12];
  const float* h0    = (const float*)d_in[13];
  const float* c0    = (const float*)d_in[14];
  float* out = (float*)d_out;
  char* ws = (char*)d_ws;

  unsigned short* U    = (unsigned short*)(ws + OFF_U);
  unsigned short* X    = (unsigned short*)(ws + OFF_X);
  unsigned short* WIH  = (unsigned short*)(ws + OFF_WIH);
  float*          BIAS = (float*)(ws + OFF_BIAS);
  unsigned int*   WQ   = (unsigned int*)(ws + OFF_WQ);
  float*          FS   = (float*)(ws + OFF_FS);
  unsigned short* WOP  = (unsigned short*)(ws + OFF_WOP);
  unsigned short* HOUT = (unsigned short*)(ws + OFF_HOUT);
  float*          FE   = (float*)(ws + OFF_FE);
  float*          P    = (float*)(ws + OFF_P);
  float*          BAL  = (float*)(ws + OFF_BAL);
  unsigned char*  BP   = (unsigned char*)(ws + OFF_BP);
  unsigned char*  M    = (unsigned char*)(ws + OFF_M);
  int*            EG   = (int*)(ws + OFF_EG);

  k_gather<<<TT, 64, 0, stream>>>(x, emb, X);
  k_wih<<<256, 256, 0, stream>>>(wihf, wihb, WIH);
  k_bias<<<8, 256, 0, stream>>>(bihf, bhhf, bihb, bhhb, BIAS);
  k_wout<<<64, 256, 0, stream>>>(wout, WOP);
  k_whh6<<<2048, 64, 0, stream>>>(whhf, whhb, WQ, FS);
  k_gemm_u<<<8192, 256, 0, stream>>>(X, WIH, BIAS, U);
  k_lstm10<<<2, 512, 0, stream>>>(U, (const uint4*)WQ, (const float4*)FS, h0, c0, HOUT);
  k_feats2<<<128, 256, 0, stream>>>(HOUT, WOP, bout, FE);
  k_vchunk<<<NCH, 64, 0, stream>>>(FE, trans, P);
  k_vscan<<<1, 64, 0, stream>>>(P, BAL);
  k_vbp<<<NCH, 64, 0, stream>>>(FE, trans, BAL, BP, M);
  k_vtag<<<1, 64, 0, stream>>>(BAL, trans, M, EG, out);
  k_vemit<<<1, 256, 0, stream>>>(EG, BP, out);
}